// Round 2
// baseline (491.884 us; speedup 1.0000x reference)
//
#include <hip/hip_runtime.h>

#define NCLS 16
#define NB 391      // ceil(100000/256) buckets of 256 node IDs
#define BSH 8       // bucket = dst >> 8, local node = dst & 255
#define TILE 4096
#define PREB 512    // blocks devoted to bhist inside pre_kernel
#define ASTR 17     // padded LDS row stride (floats): odd => local*17 spreads banks

static __device__ __forceinline__ float bflo(unsigned u) {
  return __uint_as_float(u << 16);
}
static __device__ __forceinline__ float bfhi(unsigned u) {
  return __uint_as_float(u & 0xFFFF0000u);
}
static __device__ __forceinline__ unsigned f2bf1(float f) {
  unsigned u = __float_as_uint(f);
  return (u + 0x7FFF + ((u >> 16) & 1)) >> 16;  // RNE
}
static __device__ __forceinline__ unsigned packbf(float a, float b) {
  return f2bf1(a) | (f2bf1(b) << 16);
}

// ---- fused: bucket histogram (blocks 0..PREB-1) + f32->bf16 convert (rest) ----
__global__ void pre_kernel(const int* __restrict__ dstv, int* __restrict__ bcnt, int E,
                           const float2* __restrict__ aug, unsigned* __restrict__ augh, int n2) {
  __shared__ int lh[NB];
  if (blockIdx.x < PREB) {
    for (int t = threadIdx.x; t < NB; t += 256) lh[t] = 0;
    __syncthreads();
    int stride = PREB * 256;
    for (int i = blockIdx.x * 256 + threadIdx.x; i < E; i += stride)
      atomicAdd(&lh[dstv[i] >> BSH], 1);
    __syncthreads();
    for (int t = threadIdx.x; t < NB; t += 256) {
      int v = lh[t];
      if (v) atomicAdd(&bcnt[t], v);
    }
  } else {
    int i = (blockIdx.x - PREB) * 256 + threadIdx.x;
    if (i < n2) {
      float2 v = aug[i];
      augh[i] = packbf(v.x, v.y);
    }
  }
}

// ---- exclusive scan of 391 bucket counts (single block, 512 thr) ----
__global__ void bscan_kernel(const int* __restrict__ bcnt, int* __restrict__ bbase,
                             int* __restrict__ gcur) {
  __shared__ int tmp[512];
  int t = threadIdx.x;
  int x = (t < NB) ? bcnt[t] : 0;
  tmp[t] = x;
  __syncthreads();
  for (int o = 1; o < 512; o <<= 1) {
    int v = (t >= o) ? tmp[t - o] : 0;
    __syncthreads();
    tmp[t] += v;
    __syncthreads();
  }
  if (t < NB) { int e = tmp[t] - x; bbase[t] = e; gcur[t] = e; }
  if (t == NB - 1) bbase[NB] = tmp[t];
}

// ---- bin pass: tile-local bucket sort in LDS; stage {val, gdest}; coalesced flush ----
__global__ void __launch_bounds__(256) bin_kernel(const int* __restrict__ srcv,
                                                  const int* __restrict__ dstv,
                                                  int* __restrict__ gcur,
                                                  int* __restrict__ packed, int E) {
  __shared__ int hist[NB];
  __shared__ int off[NB];
  __shared__ int delta[NB];   // gb[b] - off[b]
  __shared__ int cur[NB];
  __shared__ int part[16];
  __shared__ int2 stag[TILE];
  int tid = threadIdx.x;
  int base = blockIdx.x * TILE;
  int cnt = min(TILE, E - base);
  for (int t = tid; t < NB; t += 256) hist[t] = 0;
  __syncthreads();
  for (int k = tid; k < cnt; k += 256)
    atomicAdd(&hist[dstv[base + k] >> BSH], 1);
  __syncthreads();
  // two-level exclusive scan of hist
  if (tid < 16) {
    int s = 0;
    int lo = tid * 25, hiX = min(NB, lo + 25);
    for (int j = lo; j < hiX; j++) { int v = hist[j]; off[j] = s; s += v; }
    part[tid] = s;
  }
  __syncthreads();
  if (tid == 0) {
    int run = 0;
    for (int j = 0; j < 16; j++) { int v = part[j]; part[j] = run; run += v; }
  }
  __syncthreads();
  for (int t = tid; t < NB; t += 256) off[t] += part[t / 25];
  __syncthreads();
  // reserve global space (one atomic per nonempty bucket) + set cur/delta
  for (int t = tid; t < NB; t += 256) {
    int c = hist[t];
    int gb = c ? atomicAdd(&gcur[t], c) : 0;
    delta[t] = gb - off[t];
    cur[t] = off[t];
  }
  __syncthreads();
  // scatter: stage value + final global destination
  for (int k = tid; k < cnt; k += 256) {
    int s = srcv[base + k], d = dstv[base + k];
    int b = d >> BSH;
    int p = atomicAdd(&cur[b], 1);
    int2 w;
    w.x = s | ((d & 255) << 17);
    w.y = p + delta[b];
    stag[p] = w;
  }
  __syncthreads();
  // flush: contiguous LDS b64 reads, segment-coalesced global stores
  for (int i = tid; i < cnt; i += 256) {
    int2 w = stag[i];
    packed[w.y] = w.x;
  }
}

// ---- agg: per-bucket scatter-mean in LDS + node math ----
// one block per bucket; edges unsorted within bucket, packed word = src | local<<17.
// NOTE: class loop is STATIC-indexed (registers); runtime-indexed v[] would spill
// to scratch (localMem) and cost 10x+ (round-1 regression).
__global__ void __launch_bounds__(1024) agg_kernel(const int* __restrict__ bbase,
                                                   const int* __restrict__ packed,
                                                   const unsigned* __restrict__ augh,
                                                   unsigned* __restrict__ logs,
                                                   float* __restrict__ dvec,
                                                   double* __restrict__ acc, int N) {
  __shared__ float sacc[256 * ASTR];  // per-node class sums, stride-17 padded
  __shared__ int cnt[256];
  __shared__ float red[16];
  int tid = threadIdx.x;
  int b = blockIdx.x;
  int rbeg = bbase[b], rend = bbase[b + 1];
  for (int i = tid; i < 256 * ASTR; i += 1024) sacc[i] = 0.f;
  if (tid < 256) cnt[tid] = 0;
  __syncthreads();
  int i = rbeg + tid;
  // unroll-2: two packed loads + four uint4 gathers in flight per wait
  for (; i + 1024 < rend; i += 2048) {
    int wa = packed[i];
    int wb = packed[i + 1024];
    int sa = wa & 0x1FFFF, la = wa >> 17;
    int sb = wb & 0x1FFFF, lb = wb >> 17;
    const uint4* ga = reinterpret_cast<const uint4*>(augh + ((size_t)sa << 3));
    const uint4* gb = reinterpret_cast<const uint4*>(augh + ((size_t)sb << 3));
    uint4 a0 = ga[0], a1 = ga[1];
    uint4 b0 = gb[0], b1 = gb[1];
    atomicAdd(&cnt[la], 1);
    atomicAdd(&cnt[lb], 1);
    float* ra = sacc + la * ASTR;
    float* rb = sacc + lb * ASTR;
    atomicAdd(&ra[0],  bflo(a0.x)); atomicAdd(&ra[1],  bfhi(a0.x));
    atomicAdd(&ra[2],  bflo(a0.y)); atomicAdd(&ra[3],  bfhi(a0.y));
    atomicAdd(&ra[4],  bflo(a0.z)); atomicAdd(&ra[5],  bfhi(a0.z));
    atomicAdd(&ra[6],  bflo(a0.w)); atomicAdd(&ra[7],  bfhi(a0.w));
    atomicAdd(&ra[8],  bflo(a1.x)); atomicAdd(&ra[9],  bfhi(a1.x));
    atomicAdd(&ra[10], bflo(a1.y)); atomicAdd(&ra[11], bfhi(a1.y));
    atomicAdd(&ra[12], bflo(a1.z)); atomicAdd(&ra[13], bfhi(a1.z));
    atomicAdd(&ra[14], bflo(a1.w)); atomicAdd(&ra[15], bfhi(a1.w));
    atomicAdd(&rb[0],  bflo(b0.x)); atomicAdd(&rb[1],  bfhi(b0.x));
    atomicAdd(&rb[2],  bflo(b0.y)); atomicAdd(&rb[3],  bfhi(b0.y));
    atomicAdd(&rb[4],  bflo(b0.z)); atomicAdd(&rb[5],  bfhi(b0.z));
    atomicAdd(&rb[6],  bflo(b0.w)); atomicAdd(&rb[7],  bfhi(b0.w));
    atomicAdd(&rb[8],  bflo(b1.x)); atomicAdd(&rb[9],  bfhi(b1.x));
    atomicAdd(&rb[10], bflo(b1.y)); atomicAdd(&rb[11], bfhi(b1.y));
    atomicAdd(&rb[12], bflo(b1.z)); atomicAdd(&rb[13], bfhi(b1.z));
    atomicAdd(&rb[14], bflo(b1.w)); atomicAdd(&rb[15], bfhi(b1.w));
  }
  if (i < rend) {
    int wa = packed[i];
    int sa = wa & 0x1FFFF, la = wa >> 17;
    const uint4* ga = reinterpret_cast<const uint4*>(augh + ((size_t)sa << 3));
    uint4 a0 = ga[0], a1 = ga[1];
    atomicAdd(&cnt[la], 1);
    float* ra = sacc + la * ASTR;
    atomicAdd(&ra[0],  bflo(a0.x)); atomicAdd(&ra[1],  bfhi(a0.x));
    atomicAdd(&ra[2],  bflo(a0.y)); atomicAdd(&ra[3],  bfhi(a0.y));
    atomicAdd(&ra[4],  bflo(a0.z)); atomicAdd(&ra[5],  bfhi(a0.z));
    atomicAdd(&ra[6],  bflo(a0.w)); atomicAdd(&ra[7],  bfhi(a0.w));
    atomicAdd(&ra[8],  bflo(a1.x)); atomicAdd(&ra[9],  bfhi(a1.x));
    atomicAdd(&ra[10], bflo(a1.y)); atomicAdd(&ra[11], bfhi(a1.y));
    atomicAdd(&ra[12], bflo(a1.z)); atomicAdd(&ra[13], bfhi(a1.z));
    atomicAdd(&ra[14], bflo(a1.w)); atomicAdd(&ra[15], bfhi(a1.w));
  }
  __syncthreads();
  float contrib = 0.f;
  if (tid < 256) {
    int g = (b << BSH) + tid;
    if (g < N) {
      int deg = cnt[tid];
      float inv = 1.0f / fmaxf((float)deg, 1.0f);
      const float* row = sacc + tid * ASTR;
      float a[16];
      float p2 = 0.f;
#pragma unroll
      for (int c = 0; c < 16; c++) {
        a[c] = row[c] * inv;
        p2 += a[c] * a[c];
      }
      float ip = 1.0f / p2;
      float d[16];
      float h = 0.f;
#pragma unroll
      for (int c = 0; c < 16; c++) {
        d[c] = a[c] * a[c] * ip + 1e-10f;
        h += d[c] * __logf(d[c]);
      }
      uint4 lw0, lw1;
      lw0.x = packbf(__logf(a[0] + 1e-10f), __logf(a[1] + 1e-10f));
      lw0.y = packbf(__logf(a[2] + 1e-10f), __logf(a[3] + 1e-10f));
      lw0.z = packbf(__logf(a[4] + 1e-10f), __logf(a[5] + 1e-10f));
      lw0.w = packbf(__logf(a[6] + 1e-10f), __logf(a[7] + 1e-10f));
      lw1.x = packbf(__logf(a[8] + 1e-10f), __logf(a[9] + 1e-10f));
      lw1.y = packbf(__logf(a[10] + 1e-10f), __logf(a[11] + 1e-10f));
      lw1.z = packbf(__logf(a[12] + 1e-10f), __logf(a[13] + 1e-10f));
      lw1.w = packbf(__logf(a[14] + 1e-10f), __logf(a[15] + 1e-10f));
      uint4* lp = reinterpret_cast<uint4*>(logs + ((size_t)g << 3));
      lp[0] = lw0;
      lp[1] = lw1;
      float4* dp = reinterpret_cast<float4*>(dvec + ((size_t)g << 4));
      float4 dd;
      dd.x = d[0];  dd.y = d[1];  dd.z = d[2];  dd.w = d[3];  dp[0] = dd;
      dd.x = d[4];  dd.y = d[5];  dd.z = d[6];  dd.w = d[7];  dp[1] = dd;
      dd.x = d[8];  dd.y = d[9];  dd.z = d[10]; dd.w = d[11]; dp[2] = dd;
      dd.x = d[12]; dd.y = d[13]; dd.z = d[14]; dd.w = d[15]; dp[3] = dd;
      contrib = (float)deg * h;
    }
  }
#pragma unroll
  for (int o = 32; o >= 1; o >>= 1) contrib += __shfl_xor(contrib, o, 64);
  if ((tid & 63) == 0) red[tid >> 6] = contrib;
  __syncthreads();
  if (tid == 0) {
    float s = 0.f;
#pragma unroll
    for (int wv = 0; wv < 16; wv++) s += red[wv];
    atomicAdd(acc, (double)s);
  }
}

// ---- loss: per-bucket dvec in LDS; stream edges; gather logs[src]; dot ----
__global__ void __launch_bounds__(1024) loss_kernel(const int* __restrict__ bbase,
                                                    const int* __restrict__ packed,
                                                    const unsigned* __restrict__ logs,
                                                    const float* __restrict__ dvec,
                                                    double* __restrict__ acc, int N) {
  __shared__ float sdv[256 * ASTR];
  __shared__ float red[16];
  int tid = threadIdx.x;
  int b = blockIdx.x;
  int rbeg = bbase[b], rend = bbase[b + 1];
  int nb0 = b << BSH;
  {
    const float4* gsrc = reinterpret_cast<const float4*>(dvec + ((size_t)nb0 << 4));
    int nvalid = min(256, N - nb0);
    int nf4 = nvalid * 4;
    for (int i = tid; i < nf4; i += 1024) {
      float4 v = gsrc[i];
      float* r = sdv + (i >> 2) * ASTR + ((i & 3) << 2);
      r[0] = v.x; r[1] = v.y; r[2] = v.z; r[3] = v.w;
    }
  }
  __syncthreads();
  float dot = 0.f;
  int i = rbeg + tid;
  for (; i + 1024 < rend; i += 2048) {
    int wa = packed[i];
    int wb = packed[i + 1024];
    int sa = wa & 0x1FFFF, la = wa >> 17;
    int sb = wb & 0x1FFFF, lb = wb >> 17;
    const uint4* ga = reinterpret_cast<const uint4*>(logs + ((size_t)sa << 3));
    const uint4* gb = reinterpret_cast<const uint4*>(logs + ((size_t)sb << 3));
    uint4 a0 = ga[0], a1 = ga[1];
    uint4 b0 = gb[0], b1 = gb[1];
    const float* ra = sdv + la * ASTR;
    const float* rb = sdv + lb * ASTR;
    dot += ra[0] * bflo(a0.x) + ra[1] * bfhi(a0.x) +
           ra[2] * bflo(a0.y) + ra[3] * bfhi(a0.y) +
           ra[4] * bflo(a0.z) + ra[5] * bfhi(a0.z) +
           ra[6] * bflo(a0.w) + ra[7] * bfhi(a0.w) +
           ra[8] * bflo(a1.x) + ra[9] * bfhi(a1.x) +
           ra[10] * bflo(a1.y) + ra[11] * bfhi(a1.y) +
           ra[12] * bflo(a1.z) + ra[13] * bfhi(a1.z) +
           ra[14] * bflo(a1.w) + ra[15] * bfhi(a1.w);
    dot += rb[0] * bflo(b0.x) + rb[1] * bfhi(b0.x) +
           rb[2] * bflo(b0.y) + rb[3] * bfhi(b0.y) +
           rb[4] * bflo(b0.z) + rb[5] * bfhi(b0.z) +
           rb[6] * bflo(b0.w) + rb[7] * bfhi(b0.w) +
           rb[8] * bflo(b1.x) + rb[9] * bfhi(b1.x) +
           rb[10] * bflo(b1.y) + rb[11] * bfhi(b1.y) +
           rb[12] * bflo(b1.z) + rb[13] * bfhi(b1.z) +
           rb[14] * bflo(b1.w) + rb[15] * bfhi(b1.w);
  }
  if (i < rend) {
    int wa = packed[i];
    int sa = wa & 0x1FFFF, la = wa >> 17;
    const uint4* ga = reinterpret_cast<const uint4*>(logs + ((size_t)sa << 3));
    uint4 a0 = ga[0], a1 = ga[1];
    const float* ra = sdv + la * ASTR;
    dot += ra[0] * bflo(a0.x) + ra[1] * bfhi(a0.x) +
           ra[2] * bflo(a0.y) + ra[3] * bfhi(a0.y) +
           ra[4] * bflo(a0.z) + ra[5] * bfhi(a0.z) +
           ra[6] * bflo(a0.w) + ra[7] * bfhi(a0.w) +
           ra[8] * bflo(a1.x) + ra[9] * bfhi(a1.x) +
           ra[10] * bflo(a1.y) + ra[11] * bfhi(a1.y) +
           ra[12] * bflo(a1.z) + ra[13] * bfhi(a1.z) +
           ra[14] * bflo(a1.w) + ra[15] * bfhi(a1.w);
  }
#pragma unroll
  for (int o = 32; o >= 1; o >>= 1) dot += __shfl_xor(dot, o, 64);
  if ((tid & 63) == 0) red[tid >> 6] = dot;
  __syncthreads();
  if (tid == 0) {
    float s = 0.f;
#pragma unroll
    for (int wv = 0; wv < 16; wv++) s += red[wv];
    atomicAdd(acc, -(double)s);
  }
}

__global__ void finalize_kernel(const double* __restrict__ acc,
                                float* __restrict__ out, int E) {
  if (threadIdx.x == 0 && blockIdx.x == 0)
    out[0] = (float)(acc[0] / (double)E);
}

extern "C" void kernel_launch(void* const* d_in, const int* in_sizes, int n_in,
                              void* d_out, int out_size, void* d_ws, size_t ws_size,
                              hipStream_t stream) {
  const int* edge_index = (const int*)d_in[0];
  const float* aug_pred = (const float*)d_in[1];
  const int E = in_sizes[0] / 2;
  const int N = in_sizes[1] / NCLS;

  const int* srcv = edge_index;
  const int* dstv = edge_index + E;

  // 256B-aligned bump allocator over d_ws
  char* p = (char*)d_ws;
  auto alloc = [&](size_t bytes) {
    char* r = p;
    p += (bytes + 255) & ~(size_t)255;
    return r;
  };
  double* acc = (double*)alloc(8);
  int* bcnt = (int*)alloc(NB * 4);
  int* bbase = (int*)alloc((NB + 1) * 4);
  int* gcur = (int*)alloc(NB * 4);
  int* packed = (int*)alloc((size_t)E * 4);
  unsigned* augh = (unsigned*)alloc((size_t)N * NCLS * 2);
  unsigned* logs = (unsigned*)alloc((size_t)N * NCLS * 2);
  float* dvec = (float*)alloc((size_t)N * NCLS * 4);

  // zero acc + bcnt (contiguous prefix of the arena)
  size_t zero_bytes = (size_t)((char*)bbase - (char*)d_ws);
  hipMemsetAsync(d_ws, 0, zero_bytes, stream);

  int n2 = N * NCLS / 2;
  int cvtb = (n2 + 255) / 256;
  pre_kernel<<<PREB + cvtb, 256, 0, stream>>>(dstv, bcnt, E, (const float2*)aug_pred, augh, n2);
  bscan_kernel<<<1, 512, 0, stream>>>(bcnt, bbase, gcur);
  int tiles = (E + TILE - 1) / TILE;
  bin_kernel<<<tiles, 256, 0, stream>>>(srcv, dstv, gcur, packed, E);
  agg_kernel<<<NB, 1024, 0, stream>>>(bbase, packed, augh, logs, dvec, acc, N);
  loss_kernel<<<NB, 1024, 0, stream>>>(bbase, packed, logs, dvec, acc, N);
  finalize_kernel<<<1, 64, 0, stream>>>(acc, (float*)d_out, E);
}

// Round 3
// 178.087 us; speedup vs baseline: 2.7620x; 2.7620x over previous
//
#include <hip/hip_runtime.h>

#define NCLS 16
#define NB 391      // ceil(100000/256) buckets of 256 node IDs
#define BSH 8       // bucket = dst >> 8, local node = dst & 255
#define TILE 4096
#define PREB 512    // blocks devoted to bhist inside pre_kernel
#define BMAX 9216   // max edges per bucket (mean ~8200, sd ~90; 9216 proven by round-0 CAP)
#define ACAP 9      // per-thread edge stash: BMAX/1024

static __device__ __forceinline__ float bflo(unsigned u) {
  return __uint_as_float(u << 16);
}
static __device__ __forceinline__ float bfhi(unsigned u) {
  return __uint_as_float(u & 0xFFFF0000u);
}
static __device__ __forceinline__ unsigned f2bf1(float f) {
  unsigned u = __float_as_uint(f);
  return (u + 0x7FFF + ((u >> 16) & 1)) >> 16;  // RNE
}
static __device__ __forceinline__ unsigned packbf(float a, float b) {
  return f2bf1(a) | (f2bf1(b) << 16);
}

// ---- fused: bucket histogram (blocks 0..PREB-1) + f32->bf16 convert (rest) ----
__global__ void pre_kernel(const int* __restrict__ dstv, int* __restrict__ bcnt, int E,
                           const float2* __restrict__ aug, unsigned* __restrict__ augh, int n2) {
  __shared__ int lh[NB];
  if (blockIdx.x < PREB) {
    for (int t = threadIdx.x; t < NB; t += 256) lh[t] = 0;
    __syncthreads();
    int stride = PREB * 256;
    for (int i = blockIdx.x * 256 + threadIdx.x; i < E; i += stride)
      atomicAdd(&lh[dstv[i] >> BSH], 1);
    __syncthreads();
    for (int t = threadIdx.x; t < NB; t += 256) {
      int v = lh[t];
      if (v) atomicAdd(&bcnt[t], v);
    }
  } else {
    int i = (blockIdx.x - PREB) * 256 + threadIdx.x;
    if (i < n2) {
      float2 v = aug[i];
      augh[i] = packbf(v.x, v.y);
    }
  }
}

// ---- exclusive scan of 391 bucket counts (single block, 512 thr) ----
__global__ void bscan_kernel(const int* __restrict__ bcnt, int* __restrict__ bbase,
                             int* __restrict__ gcur) {
  __shared__ int tmp[512];
  int t = threadIdx.x;
  int x = (t < NB) ? bcnt[t] : 0;
  tmp[t] = x;
  __syncthreads();
  for (int o = 1; o < 512; o <<= 1) {
    int v = (t >= o) ? tmp[t - o] : 0;
    __syncthreads();
    tmp[t] += v;
    __syncthreads();
  }
  if (t < NB) { int e = tmp[t] - x; bbase[t] = e; gcur[t] = e; }
  if (t == NB - 1) bbase[NB] = tmp[t];
}

// ---- bin pass: tile-local bucket sort in LDS; stage {val, gdest}; coalesced flush ----
__global__ void __launch_bounds__(256) bin_kernel(const int* __restrict__ srcv,
                                                  const int* __restrict__ dstv,
                                                  int* __restrict__ gcur,
                                                  int* __restrict__ packed, int E) {
  __shared__ int hist[NB];
  __shared__ int off[NB];
  __shared__ int delta[NB];   // gb[b] - off[b]
  __shared__ int cur[NB];
  __shared__ int part[16];
  __shared__ int2 stag[TILE];
  int tid = threadIdx.x;
  int base = blockIdx.x * TILE;
  int cnt = min(TILE, E - base);
  for (int t = tid; t < NB; t += 256) hist[t] = 0;
  __syncthreads();
  for (int k = tid; k < cnt; k += 256)
    atomicAdd(&hist[dstv[base + k] >> BSH], 1);
  __syncthreads();
  // two-level exclusive scan of hist
  if (tid < 16) {
    int s = 0;
    int lo = tid * 25, hiX = min(NB, lo + 25);
    for (int j = lo; j < hiX; j++) { int v = hist[j]; off[j] = s; s += v; }
    part[tid] = s;
  }
  __syncthreads();
  if (tid == 0) {
    int run = 0;
    for (int j = 0; j < 16; j++) { int v = part[j]; part[j] = run; run += v; }
  }
  __syncthreads();
  for (int t = tid; t < NB; t += 256) off[t] += part[t / 25];
  __syncthreads();
  // reserve global space (one atomic per nonempty bucket) + set cur/delta
  for (int t = tid; t < NB; t += 256) {
    int c = hist[t];
    int gb = c ? atomicAdd(&gcur[t], c) : 0;
    delta[t] = gb - off[t];
    cur[t] = off[t];
  }
  __syncthreads();
  // scatter: stage value + final global destination
  for (int k = tid; k < cnt; k += 256) {
    int s = srcv[base + k], d = dstv[base + k];
    int b = d >> BSH;
    int p = atomicAdd(&cur[b], 1);
    int2 w;
    w.x = s | ((d & 255) << 17);
    w.y = p + delta[b];
    stag[p] = w;
  }
  __syncthreads();
  // flush: contiguous LDS b64 reads, segment-coalesced global stores
  for (int i = tid; i < cnt; i += 256) {
    int2 w = stag[i];
    packed[w.y] = w.x;
  }
}

// ---- agg: per-bucket counting sort in LDS + register accumulation + node math ----
// ZERO fp LDS atomics (round-2 lesson: LDS atomics retire ~1 lane/3cyc; 17/edge = 343us).
// One int rtn-atomic per edge gives hist AND scatter rank. Accumulation is gather-side:
// 4 lanes per node, 4 classes per lane, all sums in registers (static-indexed).
__global__ void __launch_bounds__(1024) agg_kernel(const int* __restrict__ bbase,
                                                   const int* __restrict__ packed,
                                                   const unsigned* __restrict__ augh,
                                                   unsigned* __restrict__ logs,
                                                   float* __restrict__ dvec,
                                                   double* __restrict__ acc, int N) {
  __shared__ int ssrc[BMAX];   // bucket edges' src, sorted by local node
  __shared__ int hist[256];    // per-local degree
  __shared__ int off[256];     // exclusive prefix (bucket-local CSR)
  __shared__ float red[16];
  int tid = threadIdx.x;
  int b = blockIdx.x;
  int rbeg = bbase[b], rend = bbase[b + 1];
  if (tid < 256) hist[tid] = 0;
  __syncthreads();
  // phase 1: stash edges in registers; rtn-atomic = histogram + rank in one
  int myw[ACAP];
  int myr[ACAP];
#pragma unroll
  for (int k = 0; k < ACAP; k++) {
    int i = rbeg + tid + k * 1024;
    int w = (i < rend) ? packed[i] : -1;
    myw[k] = w;
    myr[k] = (w >= 0) ? atomicAdd(&hist[w >> 17], 1) : 0;
  }
  __syncthreads();
  // phase 2: exclusive scan of hist -> off (Hillis-Steele, all threads hit barriers)
  int x = (tid < 256) ? hist[tid] : 0;
  if (tid < 256) off[tid] = x;
  __syncthreads();
  for (int o = 1; o < 256; o <<= 1) {
    int v = (tid >= o && tid < 256) ? off[tid - o] : 0;
    __syncthreads();
    if (tid < 256) off[tid] += v;
    __syncthreads();
  }
  int excl = (tid < 256) ? off[tid] - x : 0;
  __syncthreads();
  if (tid < 256) off[tid] = excl;
  __syncthreads();
  // phase 3: scatter src into sorted position (plain ds_write, no atomic)
#pragma unroll
  for (int k = 0; k < ACAP; k++) {
    int w = myw[k];
    if (w >= 0) ssrc[off[w >> 17] + myr[k]] = w & 0x1FFFF;
  }
  __syncthreads();
  // phase 4: accumulate. 4 lanes per node; lane owns classes 4L..4L+3 (uint2 gather).
  int node = tid >> 2, lane = tid & 3;
  int boff = off[node];
  int deg = hist[node];
  float s0 = 0.f, s1 = 0.f, s2 = 0.f, s3 = 0.f;
  int wsh = lane << 1;  // word offset within the node's 8-word augh row
  int e = 0;
  for (; e + 4 <= deg; e += 4) {
    int q0 = ssrc[boff + e],     q1 = ssrc[boff + e + 1];
    int q2 = ssrc[boff + e + 2], q3 = ssrc[boff + e + 3];
    uint2 g0 = *reinterpret_cast<const uint2*>(augh + ((size_t)q0 << 3) + wsh);
    uint2 g1 = *reinterpret_cast<const uint2*>(augh + ((size_t)q1 << 3) + wsh);
    uint2 g2 = *reinterpret_cast<const uint2*>(augh + ((size_t)q2 << 3) + wsh);
    uint2 g3 = *reinterpret_cast<const uint2*>(augh + ((size_t)q3 << 3) + wsh);
    s0 += bflo(g0.x) + bflo(g1.x) + bflo(g2.x) + bflo(g3.x);
    s1 += bfhi(g0.x) + bfhi(g1.x) + bfhi(g2.x) + bfhi(g3.x);
    s2 += bflo(g0.y) + bflo(g1.y) + bflo(g2.y) + bflo(g3.y);
    s3 += bfhi(g0.y) + bfhi(g1.y) + bfhi(g2.y) + bfhi(g3.y);
  }
  for (; e < deg; e++) {
    int q0 = ssrc[boff + e];
    uint2 g0 = *reinterpret_cast<const uint2*>(augh + ((size_t)q0 << 3) + wsh);
    s0 += bflo(g0.x); s1 += bfhi(g0.x);
    s2 += bflo(g0.y); s3 += bfhi(g0.y);
  }
  // phase 5: node math. p2 and h reduced across the 4-lane group via shfl.
  float inv = 1.0f / fmaxf((float)deg, 1.0f);
  float a0 = s0 * inv, a1 = s1 * inv, a2 = s2 * inv, a3 = s3 * inv;
  float p2 = a0 * a0 + a1 * a1 + a2 * a2 + a3 * a3;
  p2 += __shfl_xor(p2, 1, 64);
  p2 += __shfl_xor(p2, 2, 64);
  float ip = 1.0f / p2;
  float d0 = a0 * a0 * ip + 1e-10f, d1 = a1 * a1 * ip + 1e-10f;
  float d2 = a2 * a2 * ip + 1e-10f, d3 = a3 * a3 * ip + 1e-10f;
  float h = d0 * __logf(d0) + d1 * __logf(d1) + d2 * __logf(d2) + d3 * __logf(d3);
  h += __shfl_xor(h, 1, 64);
  h += __shfl_xor(h, 2, 64);
  int g = (b << BSH) + node;
  float contrib = 0.f;
  if (g < N) {
    uint2 lw;
    lw.x = packbf(__logf(a0 + 1e-10f), __logf(a1 + 1e-10f));
    lw.y = packbf(__logf(a2 + 1e-10f), __logf(a3 + 1e-10f));
    *reinterpret_cast<uint2*>(logs + ((size_t)g << 3) + wsh) = lw;
    float4 dd;
    dd.x = d0; dd.y = d1; dd.z = d2; dd.w = d3;
    *reinterpret_cast<float4*>(dvec + ((size_t)g << 4) + (lane << 2)) = dd;
    if (lane == 0) contrib = (float)deg * h;
  }
#pragma unroll
  for (int o = 32; o >= 1; o >>= 1) contrib += __shfl_xor(contrib, o, 64);
  if ((tid & 63) == 0) red[tid >> 6] = contrib;
  __syncthreads();
  if (tid == 0) {
    float s = 0.f;
#pragma unroll
    for (int wv = 0; wv < 16; wv++) s += red[wv];
    atomicAdd(acc, (double)s);
  }
}

// ---- loss: per-bucket dvec in LDS; stream edges; gather logs[src]; dot ----
#define ASTR 17
__global__ void __launch_bounds__(1024) loss_kernel(const int* __restrict__ bbase,
                                                    const int* __restrict__ packed,
                                                    const unsigned* __restrict__ logs,
                                                    const float* __restrict__ dvec,
                                                    double* __restrict__ acc, int N) {
  __shared__ float sdv[256 * ASTR];
  __shared__ float red[16];
  int tid = threadIdx.x;
  int b = blockIdx.x;
  int rbeg = bbase[b], rend = bbase[b + 1];
  int nb0 = b << BSH;
  {
    const float4* gsrc = reinterpret_cast<const float4*>(dvec + ((size_t)nb0 << 4));
    int nvalid = min(256, N - nb0);
    int nf4 = nvalid * 4;
    for (int i = tid; i < nf4; i += 1024) {
      float4 v = gsrc[i];
      float* r = sdv + (i >> 2) * ASTR + ((i & 3) << 2);
      r[0] = v.x; r[1] = v.y; r[2] = v.z; r[3] = v.w;
    }
  }
  __syncthreads();
  float dot = 0.f;
  int i = rbeg + tid;
  for (; i + 1024 < rend; i += 2048) {
    int wa = packed[i];
    int wb = packed[i + 1024];
    int sa = wa & 0x1FFFF, la = wa >> 17;
    int sb = wb & 0x1FFFF, lb = wb >> 17;
    const uint4* ga = reinterpret_cast<const uint4*>(logs + ((size_t)sa << 3));
    const uint4* gb = reinterpret_cast<const uint4*>(logs + ((size_t)sb << 3));
    uint4 a0 = ga[0], a1 = ga[1];
    uint4 b0 = gb[0], b1 = gb[1];
    const float* ra = sdv + la * ASTR;
    const float* rb = sdv + lb * ASTR;
    dot += ra[0] * bflo(a0.x) + ra[1] * bfhi(a0.x) +
           ra[2] * bflo(a0.y) + ra[3] * bfhi(a0.y) +
           ra[4] * bflo(a0.z) + ra[5] * bfhi(a0.z) +
           ra[6] * bflo(a0.w) + ra[7] * bfhi(a0.w) +
           ra[8] * bflo(a1.x) + ra[9] * bfhi(a1.x) +
           ra[10] * bflo(a1.y) + ra[11] * bfhi(a1.y) +
           ra[12] * bflo(a1.z) + ra[13] * bfhi(a1.z) +
           ra[14] * bflo(a1.w) + ra[15] * bfhi(a1.w);
    dot += rb[0] * bflo(b0.x) + rb[1] * bfhi(b0.x) +
           rb[2] * bflo(b0.y) + rb[3] * bfhi(b0.y) +
           rb[4] * bflo(b0.z) + rb[5] * bfhi(b0.z) +
           rb[6] * bflo(b0.w) + rb[7] * bfhi(b0.w) +
           rb[8] * bflo(b1.x) + rb[9] * bfhi(b1.x) +
           rb[10] * bflo(b1.y) + rb[11] * bfhi(b1.y) +
           rb[12] * bflo(b1.z) + rb[13] * bfhi(b1.z) +
           rb[14] * bflo(b1.w) + rb[15] * bfhi(b1.w);
  }
  if (i < rend) {
    int wa = packed[i];
    int sa = wa & 0x1FFFF, la = wa >> 17;
    const uint4* ga = reinterpret_cast<const uint4*>(logs + ((size_t)sa << 3));
    uint4 a0 = ga[0], a1 = ga[1];
    const float* ra = sdv + la * ASTR;
    dot += ra[0] * bflo(a0.x) + ra[1] * bfhi(a0.x) +
           ra[2] * bflo(a0.y) + ra[3] * bfhi(a0.y) +
           ra[4] * bflo(a0.z) + ra[5] * bfhi(a0.z) +
           ra[6] * bflo(a0.w) + ra[7] * bfhi(a0.w) +
           ra[8] * bflo(a1.x) + ra[9] * bfhi(a1.x) +
           ra[10] * bflo(a1.y) + ra[11] * bfhi(a1.y) +
           ra[12] * bflo(a1.z) + ra[13] * bfhi(a1.z) +
           ra[14] * bflo(a1.w) + ra[15] * bfhi(a1.w);
  }
#pragma unroll
  for (int o = 32; o >= 1; o >>= 1) dot += __shfl_xor(dot, o, 64);
  if ((tid & 63) == 0) red[tid >> 6] = dot;
  __syncthreads();
  if (tid == 0) {
    float s = 0.f;
#pragma unroll
    for (int wv = 0; wv < 16; wv++) s += red[wv];
    atomicAdd(acc, -(double)s);
  }
}

__global__ void finalize_kernel(const double* __restrict__ acc,
                                float* __restrict__ out, int E) {
  if (threadIdx.x == 0 && blockIdx.x == 0)
    out[0] = (float)(acc[0] / (double)E);
}

extern "C" void kernel_launch(void* const* d_in, const int* in_sizes, int n_in,
                              void* d_out, int out_size, void* d_ws, size_t ws_size,
                              hipStream_t stream) {
  const int* edge_index = (const int*)d_in[0];
  const float* aug_pred = (const float*)d_in[1];
  const int E = in_sizes[0] / 2;
  const int N = in_sizes[1] / NCLS;

  const int* srcv = edge_index;
  const int* dstv = edge_index + E;

  // 256B-aligned bump allocator over d_ws
  char* p = (char*)d_ws;
  auto alloc = [&](size_t bytes) {
    char* r = p;
    p += (bytes + 255) & ~(size_t)255;
    return r;
  };
  double* acc = (double*)alloc(8);
  int* bcnt = (int*)alloc(NB * 4);
  int* bbase = (int*)alloc((NB + 1) * 4);
  int* gcur = (int*)alloc(NB * 4);
  int* packed = (int*)alloc((size_t)E * 4);
  unsigned* augh = (unsigned*)alloc((size_t)N * NCLS * 2);
  unsigned* logs = (unsigned*)alloc((size_t)N * NCLS * 2);
  float* dvec = (float*)alloc((size_t)N * NCLS * 4);

  // zero acc + bcnt (contiguous prefix of the arena)
  size_t zero_bytes = (size_t)((char*)bbase - (char*)d_ws);
  hipMemsetAsync(d_ws, 0, zero_bytes, stream);

  int n2 = N * NCLS / 2;
  int cvtb = (n2 + 255) / 256;
  pre_kernel<<<PREB + cvtb, 256, 0, stream>>>(dstv, bcnt, E, (const float2*)aug_pred, augh, n2);
  bscan_kernel<<<1, 512, 0, stream>>>(bcnt, bbase, gcur);
  int tiles = (E + TILE - 1) / TILE;
  bin_kernel<<<tiles, 256, 0, stream>>>(srcv, dstv, gcur, packed, E);
  agg_kernel<<<NB, 1024, 0, stream>>>(bbase, packed, augh, logs, dvec, acc, N);
  loss_kernel<<<NB, 1024, 0, stream>>>(bbase, packed, logs, dvec, acc, N);
  finalize_kernel<<<1, 64, 0, stream>>>(acc, (float*)d_out, E);
}

// Round 4
// 173.391 us; speedup vs baseline: 2.8368x; 1.0271x over previous
//
#include <hip/hip_runtime.h>

#define NCLS 16
#define NB 391      // ceil(100000/256) buckets of 256 node IDs
#define BSH 8       // bucket = dst >> 8, local node = dst & 255
#define TILE 4096
#define KPT 16      // TILE/256 edges per thread in bin_kernel
#define PREB 512    // blocks devoted to bhist inside pre_kernel
#define BMAX 9216   // max edges per bucket (mean ~8200, sd ~90; 9216 proven by round-0 CAP)
#define ACAP 9      // per-thread edge stash: BMAX/1024

static __device__ __forceinline__ float bflo(unsigned u) {
  return __uint_as_float(u << 16);
}
static __device__ __forceinline__ float bfhi(unsigned u) {
  return __uint_as_float(u & 0xFFFF0000u);
}
static __device__ __forceinline__ unsigned f2bf1(float f) {
  unsigned u = __float_as_uint(f);
  return (u + 0x7FFF + ((u >> 16) & 1)) >> 16;  // RNE
}
static __device__ __forceinline__ unsigned packbf(float a, float b) {
  return f2bf1(a) | (f2bf1(b) << 16);
}

// ---- fused: bucket histogram (blocks 0..PREB-1) + f32->bf16 convert (rest) ----
__global__ void pre_kernel(const int* __restrict__ dstv, int* __restrict__ bcnt, int E,
                           const float2* __restrict__ aug, unsigned* __restrict__ augh, int n2) {
  __shared__ int lh[NB];
  if (blockIdx.x < PREB) {
    for (int t = threadIdx.x; t < NB; t += 256) lh[t] = 0;
    __syncthreads();
    int stride = PREB * 256;
    for (int i = blockIdx.x * 256 + threadIdx.x; i < E; i += stride)
      atomicAdd(&lh[dstv[i] >> BSH], 1);
    __syncthreads();
    for (int t = threadIdx.x; t < NB; t += 256) {
      int v = lh[t];
      if (v) atomicAdd(&bcnt[t], v);
    }
  } else {
    int i = (blockIdx.x - PREB) * 256 + threadIdx.x;
    if (i < n2) {
      float2 v = aug[i];
      augh[i] = packbf(v.x, v.y);
    }
  }
}

// ---- exclusive scan of 391 bucket counts (single block, 512 thr) ----
__global__ void bscan_kernel(const int* __restrict__ bcnt, int* __restrict__ bbase,
                             int* __restrict__ gcur) {
  __shared__ int tmp[512];
  int t = threadIdx.x;
  int x = (t < NB) ? bcnt[t] : 0;
  tmp[t] = x;
  __syncthreads();
  for (int o = 1; o < 512; o <<= 1) {
    int v = (t >= o) ? tmp[t - o] : 0;
    __syncthreads();
    tmp[t] += v;
    __syncthreads();
  }
  if (t < NB) { int e = tmp[t] - x; bbase[t] = e; gcur[t] = e; }
  if (t == NB - 1) bbase[NB] = tmp[t];
}

// ---- bin pass: tile-local bucket sort in LDS; stage {val, gdest}; coalesced flush ----
// ONE LDS atomic per edge (round-3 lesson: LDS atomics lane-serialize ~3cyc; the
// histogram rtn-atomic doubles as the scatter rank — the old cur[] pass is deleted).
__global__ void __launch_bounds__(256) bin_kernel(const int* __restrict__ srcv,
                                                  const int* __restrict__ dstv,
                                                  int* __restrict__ gcur,
                                                  int* __restrict__ packed, int E) {
  __shared__ int hist[NB];
  __shared__ int off[NB];
  __shared__ int delta[NB];   // gb[b] - off[b]
  __shared__ int part[16];
  __shared__ int2 stag[TILE];
  int tid = threadIdx.x;
  int base = blockIdx.x * TILE;
  int cnt = min(TILE, E - base);
  for (int t = tid; t < NB; t += 256) hist[t] = 0;
  __syncthreads();
  // phase 1: load edges, rtn-atomic = histogram + within-tile bucket rank in one.
  // myw/myp are static-indexed (registers; runtime indexing would spill to scratch).
  int myw[KPT];
  int myp[KPT];  // (bucket<<12) | rank   (b<391 -> 9b, r<4096 -> 12b)
#pragma unroll
  for (int k = 0; k < KPT; k++) {
    int idx = tid + k * 256;
    myw[k] = -1;
    myp[k] = 0;
    if (idx < cnt) {
      int s = srcv[base + idx], d = dstv[base + idx];
      int b = d >> BSH;
      int r = atomicAdd(&hist[b], 1);
      myw[k] = s | ((d & 255) << 17);
      myp[k] = (b << 12) | r;
    }
  }
  __syncthreads();
  // two-level exclusive scan of hist
  if (tid < 16) {
    int s = 0;
    int lo = tid * 25, hiX = min(NB, lo + 25);
    for (int j = lo; j < hiX; j++) { int v = hist[j]; off[j] = s; s += v; }
    part[tid] = s;
  }
  __syncthreads();
  if (tid == 0) {
    int run = 0;
    for (int j = 0; j < 16; j++) { int v = part[j]; part[j] = run; run += v; }
  }
  __syncthreads();
  for (int t = tid; t < NB; t += 256) off[t] += part[t / 25];
  __syncthreads();
  // reserve global space (one atomic per nonempty bucket) + set delta
  for (int t = tid; t < NB; t += 256) {
    int c = hist[t];
    int gb = c ? atomicAdd(&gcur[t], c) : 0;
    delta[t] = gb - off[t];
  }
  __syncthreads();
  // scatter: position = off[b] + captured rank (plain ds_write, no atomic)
#pragma unroll
  for (int k = 0; k < KPT; k++) {
    if (myw[k] >= 0) {
      int b = myp[k] >> 12, r = myp[k] & 4095;
      int p = off[b] + r;
      int2 w;
      w.x = myw[k];
      w.y = p + delta[b];
      stag[p] = w;
    }
  }
  __syncthreads();
  // flush: contiguous LDS b64 reads, segment-coalesced global stores
  for (int i = tid; i < cnt; i += 256) {
    int2 w = stag[i];
    packed[w.y] = w.x;
  }
}

// ---- agg: per-bucket counting sort in LDS + register accumulation + node math ----
// ZERO fp LDS atomics; one int rtn-atomic per edge = histogram + rank.
// Scan is single-wave (shfl) — 2 block barriers instead of 16.
__global__ void __launch_bounds__(1024) agg_kernel(const int* __restrict__ bbase,
                                                   const int* __restrict__ packed,
                                                   const unsigned* __restrict__ augh,
                                                   unsigned* __restrict__ logs,
                                                   float* __restrict__ dvec,
                                                   double* __restrict__ acc, int N) {
  __shared__ int ssrc[BMAX];   // bucket edges' src, sorted by local node
  __shared__ int hist[256];    // per-local degree
  __shared__ int off[256];     // exclusive prefix (bucket-local CSR)
  __shared__ float red[16];
  int tid = threadIdx.x;
  int b = blockIdx.x;
  int rbeg = bbase[b], rend = bbase[b + 1];
  if (tid < 256) hist[tid] = 0;
  __syncthreads();
  // phase 1: stash edges in registers; rtn-atomic = histogram + rank in one
  int myw[ACAP];
  int myr[ACAP];
#pragma unroll
  for (int k = 0; k < ACAP; k++) {
    int i = rbeg + tid + k * 1024;
    int w = (i < rend) ? packed[i] : -1;
    myw[k] = w;
    myr[k] = (w >= 0) ? atomicAdd(&hist[w >> 17], 1) : 0;
  }
  __syncthreads();
  // phase 2: exclusive scan of hist -> off, single wave (lane L owns 4 entries)
  if (tid < 64) {
    int h0 = hist[4 * tid], h1 = hist[4 * tid + 1];
    int h2 = hist[4 * tid + 2], h3 = hist[4 * tid + 3];
    int tot = h0 + h1 + h2 + h3;
    int inc = tot;
#pragma unroll
    for (int o = 1; o < 64; o <<= 1) {
      int u = __shfl_up(inc, o, 64);
      if (tid >= o) inc += u;
    }
    int exc = inc - tot;
    off[4 * tid] = exc;
    off[4 * tid + 1] = exc + h0;
    off[4 * tid + 2] = exc + h0 + h1;
    off[4 * tid + 3] = exc + h0 + h1 + h2;
  }
  __syncthreads();
  // phase 3: scatter src into sorted position (plain ds_write, no atomic)
#pragma unroll
  for (int k = 0; k < ACAP; k++) {
    int w = myw[k];
    if (w >= 0) ssrc[off[w >> 17] + myr[k]] = w & 0x1FFFF;
  }
  __syncthreads();
  // phase 4: accumulate. 4 lanes per node; lane owns classes 4L..4L+3 (uint2 gather).
  // unroll-8: 8 independent L2 gathers in flight per wait.
  int node = tid >> 2, lane = tid & 3;
  int boff = off[node];
  int deg = hist[node];
  float s0 = 0.f, s1 = 0.f, s2 = 0.f, s3 = 0.f;
  int wsh = lane << 1;  // word offset within the node's 8-word augh row
  int e = 0;
  for (; e + 8 <= deg; e += 8) {
    int q0 = ssrc[boff + e],     q1 = ssrc[boff + e + 1];
    int q2 = ssrc[boff + e + 2], q3 = ssrc[boff + e + 3];
    int q4 = ssrc[boff + e + 4], q5 = ssrc[boff + e + 5];
    int q6 = ssrc[boff + e + 6], q7 = ssrc[boff + e + 7];
    uint2 g0 = *reinterpret_cast<const uint2*>(augh + ((size_t)q0 << 3) + wsh);
    uint2 g1 = *reinterpret_cast<const uint2*>(augh + ((size_t)q1 << 3) + wsh);
    uint2 g2 = *reinterpret_cast<const uint2*>(augh + ((size_t)q2 << 3) + wsh);
    uint2 g3 = *reinterpret_cast<const uint2*>(augh + ((size_t)q3 << 3) + wsh);
    uint2 g4 = *reinterpret_cast<const uint2*>(augh + ((size_t)q4 << 3) + wsh);
    uint2 g5 = *reinterpret_cast<const uint2*>(augh + ((size_t)q5 << 3) + wsh);
    uint2 g6 = *reinterpret_cast<const uint2*>(augh + ((size_t)q6 << 3) + wsh);
    uint2 g7 = *reinterpret_cast<const uint2*>(augh + ((size_t)q7 << 3) + wsh);
    s0 += bflo(g0.x) + bflo(g1.x) + bflo(g2.x) + bflo(g3.x) +
          bflo(g4.x) + bflo(g5.x) + bflo(g6.x) + bflo(g7.x);
    s1 += bfhi(g0.x) + bfhi(g1.x) + bfhi(g2.x) + bfhi(g3.x) +
          bfhi(g4.x) + bfhi(g5.x) + bfhi(g6.x) + bfhi(g7.x);
    s2 += bflo(g0.y) + bflo(g1.y) + bflo(g2.y) + bflo(g3.y) +
          bflo(g4.y) + bflo(g5.y) + bflo(g6.y) + bflo(g7.y);
    s3 += bfhi(g0.y) + bfhi(g1.y) + bfhi(g2.y) + bfhi(g3.y) +
          bfhi(g4.y) + bfhi(g5.y) + bfhi(g6.y) + bfhi(g7.y);
  }
  for (; e < deg; e++) {
    int q0 = ssrc[boff + e];
    uint2 g0 = *reinterpret_cast<const uint2*>(augh + ((size_t)q0 << 3) + wsh);
    s0 += bflo(g0.x); s1 += bfhi(g0.x);
    s2 += bflo(g0.y); s3 += bfhi(g0.y);
  }
  // phase 5: node math. p2 and h reduced across the 4-lane group via shfl.
  float inv = 1.0f / fmaxf((float)deg, 1.0f);
  float a0 = s0 * inv, a1 = s1 * inv, a2 = s2 * inv, a3 = s3 * inv;
  float p2 = a0 * a0 + a1 * a1 + a2 * a2 + a3 * a3;
  p2 += __shfl_xor(p2, 1, 64);
  p2 += __shfl_xor(p2, 2, 64);
  float ip = 1.0f / p2;
  float d0 = a0 * a0 * ip + 1e-10f, d1 = a1 * a1 * ip + 1e-10f;
  float d2 = a2 * a2 * ip + 1e-10f, d3 = a3 * a3 * ip + 1e-10f;
  float h = d0 * __logf(d0) + d1 * __logf(d1) + d2 * __logf(d2) + d3 * __logf(d3);
  h += __shfl_xor(h, 1, 64);
  h += __shfl_xor(h, 2, 64);
  int g = (b << BSH) + node;
  float contrib = 0.f;
  if (g < N) {
    uint2 lw;
    lw.x = packbf(__logf(a0 + 1e-10f), __logf(a1 + 1e-10f));
    lw.y = packbf(__logf(a2 + 1e-10f), __logf(a3 + 1e-10f));
    *reinterpret_cast<uint2*>(logs + ((size_t)g << 3) + wsh) = lw;
    float4 dd;
    dd.x = d0; dd.y = d1; dd.z = d2; dd.w = d3;
    *reinterpret_cast<float4*>(dvec + ((size_t)g << 4) + (lane << 2)) = dd;
    if (lane == 0) contrib = (float)deg * h;
  }
#pragma unroll
  for (int o = 32; o >= 1; o >>= 1) contrib += __shfl_xor(contrib, o, 64);
  if ((tid & 63) == 0) red[tid >> 6] = contrib;
  __syncthreads();
  if (tid == 0) {
    float s = 0.f;
#pragma unroll
    for (int wv = 0; wv < 16; wv++) s += red[wv];
    atomicAdd(acc, (double)s);
  }
}

// ---- loss: per-bucket dvec in LDS; stream edges; gather logs[src]; dot ----
#define ASTR 17
__global__ void __launch_bounds__(1024) loss_kernel(const int* __restrict__ bbase,
                                                    const int* __restrict__ packed,
                                                    const unsigned* __restrict__ logs,
                                                    const float* __restrict__ dvec,
                                                    double* __restrict__ acc, int N) {
  __shared__ float sdv[256 * ASTR];
  __shared__ float red[16];
  int tid = threadIdx.x;
  int b = blockIdx.x;
  int rbeg = bbase[b], rend = bbase[b + 1];
  int nb0 = b << BSH;
  {
    const float4* gsrc = reinterpret_cast<const float4*>(dvec + ((size_t)nb0 << 4));
    int nvalid = min(256, N - nb0);
    int nf4 = nvalid * 4;
    for (int i = tid; i < nf4; i += 1024) {
      float4 v = gsrc[i];
      float* r = sdv + (i >> 2) * ASTR + ((i & 3) << 2);
      r[0] = v.x; r[1] = v.y; r[2] = v.z; r[3] = v.w;
    }
  }
  __syncthreads();
  float dot = 0.f;
  int i = rbeg + tid;
  for (; i + 1024 < rend; i += 2048) {
    int wa = packed[i];
    int wb = packed[i + 1024];
    int sa = wa & 0x1FFFF, la = wa >> 17;
    int sb = wb & 0x1FFFF, lb = wb >> 17;
    const uint4* ga = reinterpret_cast<const uint4*>(logs + ((size_t)sa << 3));
    const uint4* gb = reinterpret_cast<const uint4*>(logs + ((size_t)sb << 3));
    uint4 a0 = ga[0], a1 = ga[1];
    uint4 b0 = gb[0], b1 = gb[1];
    const float* ra = sdv + la * ASTR;
    const float* rb = sdv + lb * ASTR;
    dot += ra[0] * bflo(a0.x) + ra[1] * bfhi(a0.x) +
           ra[2] * bflo(a0.y) + ra[3] * bfhi(a0.y) +
           ra[4] * bflo(a0.z) + ra[5] * bfhi(a0.z) +
           ra[6] * bflo(a0.w) + ra[7] * bfhi(a0.w) +
           ra[8] * bflo(a1.x) + ra[9] * bfhi(a1.x) +
           ra[10] * bflo(a1.y) + ra[11] * bfhi(a1.y) +
           ra[12] * bflo(a1.z) + ra[13] * bfhi(a1.z) +
           ra[14] * bflo(a1.w) + ra[15] * bfhi(a1.w);
    dot += rb[0] * bflo(b0.x) + rb[1] * bfhi(b0.x) +
           rb[2] * bflo(b0.y) + rb[3] * bfhi(b0.y) +
           rb[4] * bflo(b0.z) + rb[5] * bfhi(b0.z) +
           rb[6] * bflo(b0.w) + rb[7] * bfhi(b0.w) +
           rb[8] * bflo(b1.x) + rb[9] * bfhi(b1.x) +
           rb[10] * bflo(b1.y) + rb[11] * bfhi(b1.y) +
           rb[12] * bflo(b1.z) + rb[13] * bfhi(b1.z) +
           rb[14] * bflo(b1.w) + rb[15] * bfhi(b1.w);
  }
  if (i < rend) {
    int wa = packed[i];
    int sa = wa & 0x1FFFF, la = wa >> 17;
    const uint4* ga = reinterpret_cast<const uint4*>(logs + ((size_t)sa << 3));
    uint4 a0 = ga[0], a1 = ga[1];
    const float* ra = sdv + la * ASTR;
    dot += ra[0] * bflo(a0.x) + ra[1] * bfhi(a0.x) +
           ra[2] * bflo(a0.y) + ra[3] * bfhi(a0.y) +
           ra[4] * bflo(a0.z) + ra[5] * bfhi(a0.z) +
           ra[6] * bflo(a0.w) + ra[7] * bfhi(a0.w) +
           ra[8] * bflo(a1.x) + ra[9] * bfhi(a1.x) +
           ra[10] * bflo(a1.y) + ra[11] * bfhi(a1.y) +
           ra[12] * bflo(a1.z) + ra[13] * bfhi(a1.z) +
           ra[14] * bflo(a1.w) + ra[15] * bfhi(a1.w);
  }
#pragma unroll
  for (int o = 32; o >= 1; o >>= 1) dot += __shfl_xor(dot, o, 64);
  if ((tid & 63) == 0) red[tid >> 6] = dot;
  __syncthreads();
  if (tid == 0) {
    float s = 0.f;
#pragma unroll
    for (int wv = 0; wv < 16; wv++) s += red[wv];
    atomicAdd(acc, -(double)s);
  }
}

__global__ void finalize_kernel(const double* __restrict__ acc,
                                float* __restrict__ out, int E) {
  if (threadIdx.x == 0 && blockIdx.x == 0)
    out[0] = (float)(acc[0] / (double)E);
}

extern "C" void kernel_launch(void* const* d_in, const int* in_sizes, int n_in,
                              void* d_out, int out_size, void* d_ws, size_t ws_size,
                              hipStream_t stream) {
  const int* edge_index = (const int*)d_in[0];
  const float* aug_pred = (const float*)d_in[1];
  const int E = in_sizes[0] / 2;
  const int N = in_sizes[1] / NCLS;

  const int* srcv = edge_index;
  const int* dstv = edge_index + E;

  // 256B-aligned bump allocator over d_ws
  char* p = (char*)d_ws;
  auto alloc = [&](size_t bytes) {
    char* r = p;
    p += (bytes + 255) & ~(size_t)255;
    return r;
  };
  double* acc = (double*)alloc(8);
  int* bcnt = (int*)alloc(NB * 4);
  int* bbase = (int*)alloc((NB + 1) * 4);
  int* gcur = (int*)alloc(NB * 4);
  int* packed = (int*)alloc((size_t)E * 4);
  unsigned* augh = (unsigned*)alloc((size_t)N * NCLS * 2);
  unsigned* logs = (unsigned*)alloc((size_t)N * NCLS * 2);
  float* dvec = (float*)alloc((size_t)N * NCLS * 4);

  // zero acc + bcnt (contiguous prefix of the arena)
  size_t zero_bytes = (size_t)((char*)bbase - (char*)d_ws);
  hipMemsetAsync(d_ws, 0, zero_bytes, stream);

  int n2 = N * NCLS / 2;
  int cvtb = (n2 + 255) / 256;
  pre_kernel<<<PREB + cvtb, 256, 0, stream>>>(dstv, bcnt, E, (const float2*)aug_pred, augh, n2);
  bscan_kernel<<<1, 512, 0, stream>>>(bcnt, bbase, gcur);
  int tiles = (E + TILE - 1) / TILE;
  bin_kernel<<<tiles, 256, 0, stream>>>(srcv, dstv, gcur, packed, E);
  agg_kernel<<<NB, 1024, 0, stream>>>(bbase, packed, augh, logs, dvec, acc, N);
  loss_kernel<<<NB, 1024, 0, stream>>>(bbase, packed, logs, dvec, acc, N);
  finalize_kernel<<<1, 64, 0, stream>>>(acc, (float*)d_out, E);
}